// Round 9
// baseline (235.545 us; speedup 1.0000x reference)
//
#include <hip/hip_runtime.h>
#include <hip/hip_bf16.h>
#include <cstdint>
#include <cmath>

typedef __bf16 bf16_t;
typedef __attribute__((ext_vector_type(8))) __bf16 bf16x8;
typedef __attribute__((ext_vector_type(4))) float f32x4;

#define LOG2E 1.4426950408889634f

constexpr int B_ = 2, T_ = 2048, C_ = 1024, H_ = 16, HD_ = 64, HD2_ = 32;
constexpr int M_ = B_ * T_;  // 4096

static __device__ __forceinline__ f32x4 mfma16(bf16x8 a, bf16x8 b, f32x4 c) {
    return __builtin_amdgcn_mfma_f32_16x16x32_bf16(a, b, c, 0, 0, 0);
}

// async global->LDS, 16B per lane; LDS dest = wave-uniform base + lane*16
#define GLL(gp, lp)                                                          \
    __builtin_amdgcn_global_load_lds(                                        \
        (const __attribute__((address_space(1))) void*)(gp),                 \
        (__attribute__((address_space(3))) void*)(lp), 16, 0, 0)

// ---------------- fused prep: cast x (16B stores), transpose+cast weights ----------------
// grid: [0,2048) x-cast, [2048,3584) Wqkv 64n x 32k tiles, [3584,4096) Wproj.
__global__ void prep(const float* __restrict__ x, bf16_t* __restrict__ xb,
                     const float* __restrict__ Wqkv, bf16_t* __restrict__ wqkvT,
                     const float* __restrict__ Wproj, bf16_t* __restrict__ wprojT) {
    const int bid = blockIdx.x, tid = threadIdx.x;
    if (bid < 2048) {  // cast x: 8 floats/thread -> one 16B store
        size_t i = ((size_t)bid * 256 + tid) * 8;
        float4 v0 = *(const float4*)(x + i);
        float4 v1 = *(const float4*)(x + i + 4);
        union { bf16_t h[8]; uint4 u; } pk;
        pk.h[0] = (bf16_t)v0.x; pk.h[1] = (bf16_t)v0.y;
        pk.h[2] = (bf16_t)v0.z; pk.h[3] = (bf16_t)v0.w;
        pk.h[4] = (bf16_t)v1.x; pk.h[5] = (bf16_t)v1.y;
        pk.h[6] = (bf16_t)v1.z; pk.h[7] = (bf16_t)v1.w;
        *(uint4*)(xb + i) = pk.u;
        return;
    }
    __shared__ float tile[32][66];  // stride 66: 2-way-max bank spread on column reads
    const float* W;
    bf16_t* WT;
    int N, nb, kb;
    if (bid < 3584) {
        int t = bid - 2048;
        W = Wqkv; WT = wqkvT; N = 3 * C_;
        nb = (t % 48) * 64; kb = (t / 48) * 32;
    } else {
        int t = bid - 3584;
        W = Wproj; WT = wprojT; N = C_;
        nb = (t & 15) * 64; kb = (t >> 4) * 32;
    }
    const int row = tid >> 3, colg = (tid & 7) * 8;  // 32 rows x 8 col-groups
    {
        const float* src = W + (size_t)(kb + row) * N + nb + colg;
        float4 a = *(const float4*)src;
        float4 b = *(const float4*)(src + 4);
        *(float2*)&tile[row][colg] = make_float2(a.x, a.y);
        *(float2*)&tile[row][colg + 2] = make_float2(a.z, a.w);
        *(float2*)&tile[row][colg + 4] = make_float2(b.x, b.y);
        *(float2*)&tile[row][colg + 6] = make_float2(b.z, b.w);
    }
    __syncthreads();
    const int n = tid >> 2, kg = (tid & 3) * 8;  // 64 cols x 4 k-groups
    union { bf16_t h[8]; uint4 u; } pk;
#pragma unroll
    for (int j = 0; j < 8; j++) pk.h[j] = (bf16_t)tile[kg + j][n];
    *(uint4*)(WT + (size_t)(nb + n) * C_ + kb + kg) = pk.u;
}

// ---------------- GEMM: C[m][n] = A[m][:] . BT[n][:] + bias ----------------
// BK=64 (halves barrier count). Global-source 16B-chunk XOR-(row&7) swizzle so the
// GLL-staged LDS image gives free bank spread on strided frag reads.
// MODE 0: tile 128x128 (NT=4), 768 blocks XCD-partitioned; qkv epilogue
//         (Q bias+RoPE *log2e/8; K bias+RoPE swizzled; V -> VTb swizzled).
// MODE 1: tile 128x64 (NT=2), 512 blocks XCD-partitioned; fp32 out + bias.
template <int MODE>
__global__ __launch_bounds__(256, 3) void gemm128(
    const bf16_t* __restrict__ A, const bf16_t* __restrict__ BT, const float* __restrict__ bias,
    int N, int K,
    bf16_t* __restrict__ Qb, bf16_t* __restrict__ Kb, bf16_t* __restrict__ VTb,
    const float* __restrict__ cosT, const float* __restrict__ sinT, float* __restrict__ out) {
    constexpr int NT = (MODE == 1) ? 2 : 4;          // 16-col frags per wave
    constexpr int BPARTS = (MODE == 1) ? 2 : 4;      // 32-row staging parts of B
    __shared__ alignas(16) bf16_t As[128 * 64];
    __shared__ alignas(16) bf16_t Bs[32 * BPARTS * 64];
    const int tid = threadIdx.x;
    const int w = tid >> 6, lane = tid & 63;
    const int quad = lane >> 4, r = lane & 15;
    const int wm = (w >> 1) * 64, wn = (w & 1) * (16 * NT);
    // XCD-partitioned decode: 8 XCDs as 4(m) x 2(n).
    const int bid = blockIdx.x;
    const int xcd = bid & 7, s = bid >> 3;
    int mb, nb;
    if (MODE == 0) {
        mb = (((xcd >> 1) << 3) + (s & 7)) << 7;         // 32 m-tiles of 128
        nb = (((xcd & 1) * 12 + (s >> 3))) << 7;         // 24 n-tiles of 128
    } else {
        mb = (((xcd >> 1) << 3) + (s & 7)) << 7;         // 32 m-tiles of 128
        nb = (((xcd & 1) << 3) + (s >> 3)) << 6;         // 16 n-tiles of 64
    }
    const int srow = tid >> 3, schunk = tid & 7;         // 32 rows x 8 chunks per part
    const int csw = (schunk ^ (srow & 7)) * 8;           // staged (swizzled) chunk
    const int koff0 = (quad ^ (r & 7)) * 8;              // frag de-swizzle, k-half 0
    const int koff1 = ((quad + 4) ^ (r & 7)) * 8;        // k-half 1

    f32x4 acc[4][NT] = {};

    const bf16_t* gA[4];
    const bf16_t* gB[BPARTS];
#pragma unroll
    for (int p = 0; p < 4; p++) gA[p] = A + (size_t)(mb + p * 32 + srow) * K + csw;
#pragma unroll
    for (int p = 0; p < BPARTS; p++) gB[p] = BT + (size_t)(nb + p * 32 + srow) * K + csw;

    for (int k0 = 0; k0 < K; k0 += 64) {
        __syncthreads();  // previous iter's LDS reads done
#pragma unroll
        for (int p = 0; p < 4; p++) GLL(gA[p] + k0, As + p * 2048 + tid * 8);
#pragma unroll
        for (int p = 0; p < BPARTS; p++) GLL(gB[p] + k0, Bs + p * 2048 + tid * 8);
        __syncthreads();  // drains vmcnt -> LDS populated
#pragma unroll
        for (int h = 0; h < 2; h++) {
            const int ko = h ? koff1 : koff0;
            bf16x8 af[4], bfr[NT];
#pragma unroll
            for (int i = 0; i < 4; i++) af[i] = *(const bf16x8*)(As + (wm + i * 16 + r) * 64 + ko);
#pragma unroll
            for (int j = 0; j < NT; j++) bfr[j] = *(const bf16x8*)(Bs + (wn + j * 16 + r) * 64 + ko);
#pragma unroll
            for (int i = 0; i < 4; i++)
#pragma unroll
                for (int j = 0; j < NT; j++) acc[i][j] = mfma16(af[i], bfr[j], acc[i][j]);
        }
    }

    if (MODE == 0) {
        const int col_base = nb + wn;          // multiple of 64 -> one head
        const int region = col_base >> 10;     // 0=q 1=k 2=v
        const int h = (col_base & 1023) >> 6;
        const float qscale = 0.125f * LOG2E;   // fold 1/sqrt(64) and log2(e) into q
        if (region < 2) {
#pragma unroll
            for (int i = 0; i < 4; i++) {
#pragma unroll
                for (int g = 0; g < 4; g++) {
                    int m = mb + wm + i * 16 + quad * 4 + g;
                    int b = m >> 11, t = m & (T_ - 1);
                    bf16_t* dst = (region == 0 ? Qb : Kb) + ((size_t)((b * H_ + h) * T_ + t)) * 64;
                    int tw = t & 7;
#pragma unroll
                    for (int j = 0; j < 2; j++) {
                        int d = j * 16 + r;
                        float u1 = acc[i][j][g] + bias[col_base + d];
                        float u2 = acc[i][j + 2][g] + bias[col_base + d + 32];
                        float c = cosT[t * HD2_ + d], s2 = sinT[t * HD2_ + d];
                        float o1 = u1 * c - u2 * s2;
                        float o2 = u1 * s2 + u2 * c;
                        if (region == 0) {
                            dst[d] = (bf16_t)(o1 * qscale);
                            dst[d + 32] = (bf16_t)(o2 * qscale);
                        } else {  // K: chunk-swizzled within row
                            dst[((((d >> 3) ^ tw)) << 3) | (d & 7)] = (bf16_t)o1;
                            dst[(((((d + 32) >> 3) ^ tw)) << 3) | (d & 7)] = (bf16_t)o2;
                        }
                    }
                }
            }
        } else {  // V -> VT, chunk-swizzled within each 64-col tile, 8B packed stores
#pragma unroll
            for (int i = 0; i < 4; i++) {
                int m0 = mb + wm + i * 16 + quad * 4;
                int b = m0 >> 11, t0 = m0 & (T_ - 1);
                bf16_t* base = VTb + (size_t)(b * H_ + h) * 64 * T_;
#pragma unroll
                for (int j = 0; j < 4; j++) {
                    int d = j * 16 + r;
                    float bb = bias[col_base + d];
                    bf16_t pk[4];
#pragma unroll
                    for (int g = 0; g < 4; g++) pk[g] = (bf16_t)(acc[i][j][g] + bb);
                    int c = (((t0 >> 3) & 7) ^ (d & 7));
                    int tsw = (t0 & ~63) | (c << 3) | (t0 & 7);
                    *(uint64_t*)(base + (size_t)d * T_ + tsw) = *(uint64_t*)pk;
                }
            }
        }
    } else {
#pragma unroll
        for (int i = 0; i < 4; i++)
#pragma unroll
            for (int g = 0; g < 4; g++) {
                int m = mb + wm + i * 16 + quad * 4 + g;
#pragma unroll
                for (int j = 0; j < NT; j++) {
                    int col = nb + wn + j * 16 + r;
                    out[(size_t)m * N + col] = acc[i][j][g] + bias[col];
                }
            }
    }
}

// ---------------- flash attention (causal), split-K, V in registers ----------------
// K tiles staged via GLL (LDS, dbuf); V^T A-frags loaded DIRECTLY global->register
// (lane-contiguous 16B in VTb's swizzled layout), issued right after the barrier so
// QK+softmax hides their latency. LDS = 48 KB -> 3 blocks/CU (24 waves).
// Block = 512 thr (8 waves), one 64-row qtile t; groups 0/1 take even/odd KV tiles.
// 1024 blocks in DESCENDING-t order (LPT backfill).
__global__ __launch_bounds__(512, 6) void attn64(
    const bf16_t* __restrict__ Qb, const bf16_t* __restrict__ Kb,
    const bf16_t* __restrict__ VTb, bf16_t* __restrict__ att) {
    __shared__ alignas(16) bf16_t Ks[2][2][4096];  // [buf][tile parity][64x64] = 32 KB
    __shared__ alignas(16) bf16_t Ps[8][1024];     // 16 KB
    const int tid = threadIdx.x;
    const int w = tid >> 6, lane = tid & 63;
    const int grp = w >> 2, wq = w & 3;
    const int quad = lane >> 4, r = lane & 15;
    const int id = blockIdx.x;
    const int t = 31 - (id >> 5);   // descending length
    const int bh = id & 31;
    const int ntiles = t + 1, nstages = (t + 2) >> 1;
    const size_t kbase = (size_t)bh * T_ * 64;
    const size_t vbase = (size_t)bh * 64 * T_;
    bf16_t* Pw = &Ps[w][0];
    const int srow = tid >> 3, schunk = tid & 7;  // staging: 64 rows x 8 chunks = 512 thr
    const int koff0 = ((quad ^ (r & 7)) * 8);
    const int koff1 = (((quad + 4) ^ (r & 7)) * 8);

    const int qrow = t * 64 + wq * 16 + r;  // this lane's softmax column (both groups same q)
    bf16x8 qf0 = *(const bf16x8*)(Qb + kbase + (size_t)qrow * 64 + quad * 8);
    bf16x8 qf1 = *(const bf16x8*)(Qb + kbase + (size_t)qrow * 64 + 32 + quad * 8);

    f32x4 oacc[4] = {};
    float l = 0.f;  // per-lane partial row-sum

    auto stageK = [&](int jt0, int jt1, int buf) {  // one GLL per 64x64 tile (512 thr x 16B)
        GLL(Kb + kbase + (size_t)(jt0 * 64 + srow) * 64 + schunk * 8, &Ks[buf][0][0] + tid * 8);
        GLL(Kb + kbase + (size_t)(jt1 * 64 + srow) * 64 + schunk * 8, &Ks[buf][1][0] + tid * 8);
    };
    stageK(0, min(1, t), 0);
    for (int s = 0; s < nstages; s++) {
        const int cur = s & 1;
        const int jt = 2 * s + grp;
        const int jtc = min(jt, t);
        __syncthreads();  // buf[cur] staged; buf[cur^1] readers done
        // V^T A-frags straight from global (swizzled chunks match koff), issued early
        bf16x8 vf[4][2];
        {
            const bf16_t* vrow = VTb + vbase + (size_t)r * T_ + jtc * 64;
#pragma unroll
            for (int d0 = 0; d0 < 4; d0++) {
                const bf16_t* vp = vrow + (size_t)(d0 * 16) * T_;
                vf[d0][0] = *(const bf16x8*)(vp + koff0);
                vf[d0][1] = *(const bf16x8*)(vp + koff1);
            }
        }
        // prefetch next K pair (clamped indices -> deterministic vmcnt for compiler)
        {
            const int ja = 2 * (s + 1);
            stageK(min(ja, t), min(ja + 1, t), cur ^ 1);
        }
        if (jt < ntiles) {
            const bf16_t* Kt = &Ks[cur][grp][0];
            // S^T = K Q^T
            f32x4 sc[4];
#pragma unroll
            for (int m0 = 0; m0 < 4; m0++) {
                const bf16_t* kp = Kt + (m0 * 16 + r) * 64;
                bf16x8 kf0 = *(const bf16x8*)(kp + koff0);
                bf16x8 kf1 = *(const bf16x8*)(kp + koff1);
                f32x4 z = {0.f, 0.f, 0.f, 0.f};
                z = mfma16(kf0, qf0, z);
                z = mfma16(kf1, qf1, z);
                sc[m0] = z;
            }
            if (jt == t) {  // causal mask on diagonal tile (exp2(-inf)=0)
                const int j0 = jt * 64;
#pragma unroll
                for (int m0 = 0; m0 < 4; m0++) {
                    int kvb = j0 + m0 * 16 + quad * 4;
#pragma unroll
                    for (int g = 0; g < 4; g++)
                        if (kvb + g > qrow) sc[m0][g] = -INFINITY;
                }
            }
            // stateless softmax: p = exp2(s) (log2e/8 prescale makes this safe), partial l
            float rs = 0.f;
#pragma unroll
            for (int m0 = 0; m0 < 4; m0++)
#pragma unroll
                for (int g = 0; g < 4; g++) {
                    float pp = __builtin_amdgcn_exp2f(sc[m0][g]);
                    sc[m0][g] = pp;
                    rs += pp;
                }
            l += rs;
            // P^T -> per-wave LDS (packed b64), read back as B-frags
#pragma unroll
            for (int m0 = 0; m0 < 4; m0++) {
                bf16_t hq[4];
#pragma unroll
                for (int g = 0; g < 4; g++) hq[g] = (bf16_t)sc[m0][g];
                int elem = (m0 >> 1) * 512 + (((m0 & 1) * 2 + (quad >> 1)) * 16 + r) * 8 + (quad & 1) * 4;
                *(uint64_t*)(Pw + elem) = *(uint64_t*)hq;
            }
            __builtin_amdgcn_wave_barrier();  // Pw writes -> reads (same wave, DS in-order)
            bf16x8 pf0 = *(const bf16x8*)(Pw + lane * 8);
            bf16x8 pf1 = *(const bf16x8*)(Pw + 512 + lane * 8);
#pragma unroll
            for (int d0 = 0; d0 < 4; d0++) {
                oacc[d0] = mfma16(vf[d0][0], pf0, oacc[d0]);
                oacc[d0] = mfma16(vf[d0][1], pf1, oacc[d0]);
            }
        }
    }
    // full row-sum: reduce l across the 4 quads (deferred from the loop)
    l += __shfl_xor(l, 16);
    l += __shfl_xor(l, 32);
    // ---- combine group partials (split-K merge) ----
    __syncthreads();  // all staging/P traffic (incl. clamped dummy GLLs) drained
    float* Co = (float*)&Ks[0][0][0];  // O1: [wq][16q][64d] fp32 = 16 KB
    float* Cl = Co + 4096;             // l1[64]
    if (grp == 1) {
#pragma unroll
        for (int d0 = 0; d0 < 4; d0++)
            *(f32x4*)(Co + wq * 1024 + r * 64 + d0 * 16 + quad * 4) = oacc[d0];
        if (quad == 0) Cl[wq * 16 + r] = l;
    }
    __syncthreads();
    if (grp == 0) {
        float inv = 1.f / (l + Cl[wq * 16 + r]);
        const int b = bh >> 4, h = bh & 15;
        bf16_t* dst = att + ((size_t)(b * T_ + qrow)) * 1024 + h * 64;
#pragma unroll
        for (int d0 = 0; d0 < 4; d0++) {
            f32x4 o1 = *(const f32x4*)(Co + wq * 1024 + r * 64 + d0 * 16 + quad * 4);
            bf16_t hh[4];
#pragma unroll
            for (int g = 0; g < 4; g++)
                hh[g] = (bf16_t)((oacc[d0][g] + o1[g]) * inv);
            *(uint64_t*)(dst + d0 * 16 + quad * 4) = *(uint64_t*)hh;
        }
    }
}

// ---------------- launch ----------------
extern "C" void kernel_launch(void* const* d_in, const int* in_sizes, int n_in,
                              void* d_out, int out_size, void* d_ws, size_t ws_size,
                              hipStream_t stream) {
    const float* x = (const float*)d_in[0];
    const float* fcos = (const float*)d_in[1];
    const float* fsin = (const float*)d_in[2];
    const float* Wqkv = (const float*)d_in[3];
    const float* bqkv = (const float*)d_in[4];
    const float* Wproj = (const float*)d_in[5];
    const float* bproj = (const float*)d_in[6];
    float* out = (float*)d_out;

    uint8_t* p = (uint8_t*)d_ws;
    size_t need = 0;
    auto take = [&](size_t bytes) {
        void* q = p;
        size_t pad = (bytes + 255) & ~(size_t)255;
        p += pad;
        need += pad;
        return q;
    };
    bf16_t* xb = (bf16_t*)take((size_t)M_ * C_ * 2);         // 8 MB
    bf16_t* wqkvT = (bf16_t*)take((size_t)3 * C_ * C_ * 2);  // 6 MB
    bf16_t* wprojT = (bf16_t*)take((size_t)C_ * C_ * 2);     // 2 MB
    bf16_t* Qb = (bf16_t*)take((size_t)B_ * H_ * T_ * 64 * 2);
    bf16_t* Kb = (bf16_t*)take((size_t)B_ * H_ * T_ * 64 * 2);
    bf16_t* VTb = (bf16_t*)take((size_t)B_ * H_ * 64 * T_ * 2);
    bf16_t* attb = (bf16_t*)take((size_t)M_ * C_ * 2);
    if (ws_size < need) return;  // fail loudly (zeros) rather than corrupt

    // fused prep: cast x (2048) + transpose Wqkv (1536) + transpose Wproj (512)
    prep<<<4096, 256, 0, stream>>>(x, xb, Wqkv, wqkvT, Wproj, wprojT);

    // QKV GEMM + bias + RoPE + swizzled scatter (768 blocks, XCD-partitioned 1D, BK=64)
    gemm128<0><<<dim3(768), 256, 0, stream>>>(
        xb, wqkvT, bqkv, 3 * C_, C_, Qb, Kb, VTb, fcos, fsin, nullptr);

    // flash attention (split-K, V-in-registers, 3 blocks/CU, descending-t LPT)
    attn64<<<dim3(1024), 512, 0, stream>>>(Qb, Kb, VTb, attb);

    // output projection (512 blocks of 128x64, 2/CU, XCD-partitioned 1D, BK=64)
    gemm128<1><<<dim3(512), 256, 0, stream>>>(
        attb, wprojT, bproj, C_, C_, nullptr, nullptr, nullptr, nullptr, nullptr, out);
}

// Round 10
// 179.506 us; speedup vs baseline: 1.3122x; 1.3122x over previous
//
#include <hip/hip_runtime.h>
#include <hip/hip_bf16.h>
#include <cstdint>
#include <cmath>

typedef __bf16 bf16_t;
typedef __attribute__((ext_vector_type(8))) __bf16 bf16x8;
typedef __attribute__((ext_vector_type(4))) float f32x4;

#define LOG2E 1.4426950408889634f

constexpr int B_ = 2, T_ = 2048, C_ = 1024, H_ = 16, HD_ = 64, HD2_ = 32;
constexpr int M_ = B_ * T_;  // 4096

static __device__ __forceinline__ f32x4 mfma16(bf16x8 a, bf16x8 b, f32x4 c) {
    return __builtin_amdgcn_mfma_f32_16x16x32_bf16(a, b, c, 0, 0, 0);
}

// async global->LDS, 16B per lane; LDS dest = wave-uniform base + lane*16
#define GLL(gp, lp)                                                          \
    __builtin_amdgcn_global_load_lds(                                        \
        (const __attribute__((address_space(1))) void*)(gp),                 \
        (__attribute__((address_space(3))) void*)(lp), 16, 0, 0)

// ---------------- fused prep: cast x (16B stores), transpose+cast weights ----------------
// grid: [0,2048) x-cast, [2048,3584) Wqkv 64n x 32k tiles, [3584,4096) Wproj.
__global__ void prep(const float* __restrict__ x, bf16_t* __restrict__ xb,
                     const float* __restrict__ Wqkv, bf16_t* __restrict__ wqkvT,
                     const float* __restrict__ Wproj, bf16_t* __restrict__ wprojT) {
    const int bid = blockIdx.x, tid = threadIdx.x;
    if (bid < 2048) {  // cast x: 8 floats/thread -> one 16B store
        size_t i = ((size_t)bid * 256 + tid) * 8;
        float4 v0 = *(const float4*)(x + i);
        float4 v1 = *(const float4*)(x + i + 4);
        union { bf16_t h[8]; uint4 u; } pk;
        pk.h[0] = (bf16_t)v0.x; pk.h[1] = (bf16_t)v0.y;
        pk.h[2] = (bf16_t)v0.z; pk.h[3] = (bf16_t)v0.w;
        pk.h[4] = (bf16_t)v1.x; pk.h[5] = (bf16_t)v1.y;
        pk.h[6] = (bf16_t)v1.z; pk.h[7] = (bf16_t)v1.w;
        *(uint4*)(xb + i) = pk.u;
        return;
    }
    __shared__ float tile[32][66];  // stride 66: 2-way-max bank spread on column reads
    const float* W;
    bf16_t* WT;
    int N, nb, kb;
    if (bid < 3584) {
        int t = bid - 2048;
        W = Wqkv; WT = wqkvT; N = 3 * C_;
        nb = (t % 48) * 64; kb = (t / 48) * 32;
    } else {
        int t = bid - 3584;
        W = Wproj; WT = wprojT; N = C_;
        nb = (t & 15) * 64; kb = (t >> 4) * 32;
    }
    const int row = tid >> 3, colg = (tid & 7) * 8;  // 32 rows x 8 col-groups
    {
        const float* src = W + (size_t)(kb + row) * N + nb + colg;
        float4 a = *(const float4*)src;
        float4 b = *(const float4*)(src + 4);
        *(float2*)&tile[row][colg] = make_float2(a.x, a.y);
        *(float2*)&tile[row][colg + 2] = make_float2(a.z, a.w);
        *(float2*)&tile[row][colg + 4] = make_float2(b.x, b.y);
        *(float2*)&tile[row][colg + 6] = make_float2(b.z, b.w);
    }
    __syncthreads();
    const int n = tid >> 2, kg = (tid & 3) * 8;  // 64 cols x 4 k-groups
    union { bf16_t h[8]; uint4 u; } pk;
#pragma unroll
    for (int j = 0; j < 8; j++) pk.h[j] = (bf16_t)tile[kg + j][n];
    *(uint4*)(WT + (size_t)(nb + n) * C_ + kb + kg) = pk.u;
}

// ---------------- GEMM: C[m][n] = A[m][:] . BT[n][:] + bias ----------------
// BK=64 (halves barrier count). Global-source 16B-chunk XOR-(row&7) swizzle so the
// GLL-staged LDS image gives free bank spread on strided frag reads.
// MODE 0: tile 128x128 (NT=4), 768 blocks XCD-partitioned; qkv epilogue
//         (Q bias+RoPE *log2e/8; K bias+RoPE swizzled; V -> VTb swizzled).
// MODE 1: tile 128x64 (NT=2), 512 blocks XCD-partitioned; fp32 out + bias.
template <int MODE>
__global__ __launch_bounds__(256, 3) void gemm128(
    const bf16_t* __restrict__ A, const bf16_t* __restrict__ BT, const float* __restrict__ bias,
    int N, int K,
    bf16_t* __restrict__ Qb, bf16_t* __restrict__ Kb, bf16_t* __restrict__ VTb,
    const float* __restrict__ cosT, const float* __restrict__ sinT, float* __restrict__ out) {
    constexpr int NT = (MODE == 1) ? 2 : 4;          // 16-col frags per wave
    constexpr int BPARTS = (MODE == 1) ? 2 : 4;      // 32-row staging parts of B
    __shared__ alignas(16) bf16_t As[128 * 64];
    __shared__ alignas(16) bf16_t Bs[32 * BPARTS * 64];
    const int tid = threadIdx.x;
    const int w = tid >> 6, lane = tid & 63;
    const int quad = lane >> 4, r = lane & 15;
    const int wm = (w >> 1) * 64, wn = (w & 1) * (16 * NT);
    // XCD-partitioned decode: 8 XCDs as 4(m) x 2(n).
    const int bid = blockIdx.x;
    const int xcd = bid & 7, s = bid >> 3;
    int mb, nb;
    if (MODE == 0) {
        mb = (((xcd >> 1) << 3) + (s & 7)) << 7;         // 32 m-tiles of 128
        nb = (((xcd & 1) * 12 + (s >> 3))) << 7;         // 24 n-tiles of 128
    } else {
        mb = (((xcd >> 1) << 3) + (s & 7)) << 7;         // 32 m-tiles of 128
        nb = (((xcd & 1) << 3) + (s >> 3)) << 6;         // 16 n-tiles of 64
    }
    const int srow = tid >> 3, schunk = tid & 7;         // 32 rows x 8 chunks per part
    const int csw = (schunk ^ (srow & 7)) * 8;           // staged (swizzled) chunk
    const int koff0 = (quad ^ (r & 7)) * 8;              // frag de-swizzle, k-half 0
    const int koff1 = ((quad + 4) ^ (r & 7)) * 8;        // k-half 1

    f32x4 acc[4][NT] = {};

    const bf16_t* gA[4];
    const bf16_t* gB[BPARTS];
#pragma unroll
    for (int p = 0; p < 4; p++) gA[p] = A + (size_t)(mb + p * 32 + srow) * K + csw;
#pragma unroll
    for (int p = 0; p < BPARTS; p++) gB[p] = BT + (size_t)(nb + p * 32 + srow) * K + csw;

    for (int k0 = 0; k0 < K; k0 += 64) {
        __syncthreads();  // previous iter's LDS reads done
#pragma unroll
        for (int p = 0; p < 4; p++) GLL(gA[p] + k0, As + p * 2048 + tid * 8);
#pragma unroll
        for (int p = 0; p < BPARTS; p++) GLL(gB[p] + k0, Bs + p * 2048 + tid * 8);
        __syncthreads();  // drains vmcnt -> LDS populated
#pragma unroll
        for (int h = 0; h < 2; h++) {
            const int ko = h ? koff1 : koff0;
            bf16x8 af[4], bfr[NT];
#pragma unroll
            for (int i = 0; i < 4; i++) af[i] = *(const bf16x8*)(As + (wm + i * 16 + r) * 64 + ko);
#pragma unroll
            for (int j = 0; j < NT; j++) bfr[j] = *(const bf16x8*)(Bs + (wn + j * 16 + r) * 64 + ko);
#pragma unroll
            for (int i = 0; i < 4; i++)
#pragma unroll
                for (int j = 0; j < NT; j++) acc[i][j] = mfma16(af[i], bfr[j], acc[i][j]);
        }
    }

    if (MODE == 0) {
        const int col_base = nb + wn;          // multiple of 64 -> one head
        const int region = col_base >> 10;     // 0=q 1=k 2=v
        const int h = (col_base & 1023) >> 6;
        const float qscale = 0.125f * LOG2E;   // fold 1/sqrt(64) and log2(e) into q
        if (region < 2) {
#pragma unroll
            for (int i = 0; i < 4; i++) {
#pragma unroll
                for (int g = 0; g < 4; g++) {
                    int m = mb + wm + i * 16 + quad * 4 + g;
                    int b = m >> 11, t = m & (T_ - 1);
                    bf16_t* dst = (region == 0 ? Qb : Kb) + ((size_t)((b * H_ + h) * T_ + t)) * 64;
                    int tw = t & 7;
#pragma unroll
                    for (int j = 0; j < 2; j++) {
                        int d = j * 16 + r;
                        float u1 = acc[i][j][g] + bias[col_base + d];
                        float u2 = acc[i][j + 2][g] + bias[col_base + d + 32];
                        float c = cosT[t * HD2_ + d], s2 = sinT[t * HD2_ + d];
                        float o1 = u1 * c - u2 * s2;
                        float o2 = u1 * s2 + u2 * c;
                        if (region == 0) {
                            dst[d] = (bf16_t)(o1 * qscale);
                            dst[d + 32] = (bf16_t)(o2 * qscale);
                        } else {  // K: chunk-swizzled within row
                            dst[((((d >> 3) ^ tw)) << 3) | (d & 7)] = (bf16_t)o1;
                            dst[(((((d + 32) >> 3) ^ tw)) << 3) | (d & 7)] = (bf16_t)o2;
                        }
                    }
                }
            }
        } else {  // V -> VT, chunk-swizzled within each 64-col tile, 8B packed stores
#pragma unroll
            for (int i = 0; i < 4; i++) {
                int m0 = mb + wm + i * 16 + quad * 4;
                int b = m0 >> 11, t0 = m0 & (T_ - 1);
                bf16_t* base = VTb + (size_t)(b * H_ + h) * 64 * T_;
#pragma unroll
                for (int j = 0; j < 4; j++) {
                    int d = j * 16 + r;
                    float bb = bias[col_base + d];
                    bf16_t pk[4];
#pragma unroll
                    for (int g = 0; g < 4; g++) pk[g] = (bf16_t)(acc[i][j][g] + bb);
                    int c = (((t0 >> 3) & 7) ^ (d & 7));
                    int tsw = (t0 & ~63) | (c << 3) | (t0 & 7);
                    *(uint64_t*)(base + (size_t)d * T_ + tsw) = *(uint64_t*)pk;
                }
            }
        }
    } else {
#pragma unroll
        for (int i = 0; i < 4; i++)
#pragma unroll
            for (int g = 0; g < 4; g++) {
                int m = mb + wm + i * 16 + quad * 4 + g;
#pragma unroll
                for (int j = 0; j < NT; j++) {
                    int col = nb + wn + j * 16 + r;
                    out[(size_t)m * N + col] = acc[i][j][g] + bias[col];
                }
            }
    }
}

// ---------------- flash attention (causal), split-K, NO online max ----------------
// R8-validated configuration (V staged in LDS; launch_bounds(512,4) -> no spill).
// Scores carry log2e/8 prescale; p = exp2(s) raw is fp32-safe. Per-stage softmax =
// 16 exp2 + adds; l reduced across quads/groups ONCE at end.
// Block = 512 thr (8 waves), one 64-row qtile t; groups 0/1 take even/odd KV tiles.
// 1024 blocks in DESCENDING-t order (LPT backfill over 2 blocks/CU).
__global__ __launch_bounds__(512, 4) void attn64(
    const bf16_t* __restrict__ Qb, const bf16_t* __restrict__ Kb,
    const bf16_t* __restrict__ VTb, bf16_t* __restrict__ att) {
    __shared__ alignas(16) bf16_t Ks[2][2][4096];  // [buf][tile parity][64x64]
    __shared__ alignas(16) bf16_t Vs[2][2][4096];
    __shared__ alignas(16) bf16_t Ps[8][1024];
    const int tid = threadIdx.x;
    const int w = tid >> 6, lane = tid & 63;
    const int grp = w >> 2, wq = w & 3;
    const int quad = lane >> 4, r = lane & 15;
    const int id = blockIdx.x;
    const int t = 31 - (id >> 5);   // descending length
    const int bh = id & 31;
    const int ntiles = t + 1, nstages = (t + 2) >> 1;
    const size_t kbase = (size_t)bh * T_ * 64;
    const size_t vbase = (size_t)bh * 64 * T_;
    bf16_t* Pw = &Ps[w][0];
    const int srow = tid >> 3, schunk = tid & 7;  // staging: 64 rows x 8 chunks = 512 thr
    const int koff0 = ((quad ^ (r & 7)) * 8);
    const int koff1 = (((quad + 4) ^ (r & 7)) * 8);

    const int qrow = t * 64 + wq * 16 + r;  // this lane's softmax column (both groups same q)
    bf16x8 qf0 = *(const bf16x8*)(Qb + kbase + (size_t)qrow * 64 + quad * 8);
    bf16x8 qf1 = *(const bf16x8*)(Qb + kbase + (size_t)qrow * 64 + 32 + quad * 8);

    f32x4 oacc[4] = {};
    float l = 0.f;  // per-lane partial row-sum

    // stage s=0 (tiles 0 and 1)
    {
        const bf16_t* kg = Kb + kbase + (size_t)srow * 64 + schunk * 8;
        GLL(kg, &Ks[0][0][0] + tid * 8);
        const bf16_t* vg = VTb + vbase + (size_t)srow * T_ + schunk * 8;
        GLL(vg, &Vs[0][0][0] + tid * 8);
        if (1 < ntiles) {
            GLL(kg + 64 * 64, &Ks[0][1][0] + tid * 8);
            GLL(vg + 64, &Vs[0][1][0] + tid * 8);
        }
    }
    for (int s = 0; s < nstages; s++) {
        const int cur = s & 1;
        __syncthreads();  // buf[cur] staged; buf[cur^1] readers done
        if (s + 1 < nstages) {
            const int ja = 2 * (s + 1);
            const bf16_t* kg = Kb + kbase + (size_t)(ja * 64 + srow) * 64 + schunk * 8;
            const bf16_t* vg = VTb + vbase + (size_t)srow * T_ + ja * 64 + schunk * 8;
            GLL(kg, &Ks[cur ^ 1][0][0] + tid * 8);
            GLL(vg, &Vs[cur ^ 1][0][0] + tid * 8);
            if (ja + 1 < ntiles) {
                GLL(kg + 64 * 64, &Ks[cur ^ 1][1][0] + tid * 8);
                GLL(vg + 64, &Vs[cur ^ 1][1][0] + tid * 8);
            }
        }
        const int jt = 2 * s + grp;
        if (jt < ntiles) {
            const bf16_t* Kt = &Ks[cur][grp][0];
            const bf16_t* Vt = &Vs[cur][grp][0];
            // S^T = K Q^T
            f32x4 sc[4];
#pragma unroll
            for (int m0 = 0; m0 < 4; m0++) {
                const bf16_t* kp = Kt + (m0 * 16 + r) * 64;
                bf16x8 kf0 = *(const bf16x8*)(kp + koff0);
                bf16x8 kf1 = *(const bf16x8*)(kp + koff1);
                f32x4 z = {0.f, 0.f, 0.f, 0.f};
                z = mfma16(kf0, qf0, z);
                z = mfma16(kf1, qf1, z);
                sc[m0] = z;
            }
            if (jt == t) {  // causal mask on diagonal tile (exp2(-inf)=0)
                const int j0 = jt * 64;
#pragma unroll
                for (int m0 = 0; m0 < 4; m0++) {
                    int kvb = j0 + m0 * 16 + quad * 4;
#pragma unroll
                    for (int g = 0; g < 4; g++)
                        if (kvb + g > qrow) sc[m0][g] = -INFINITY;
                }
            }
            // stateless softmax: p = exp2(s), partial l
            float rs = 0.f;
#pragma unroll
            for (int m0 = 0; m0 < 4; m0++)
#pragma unroll
                for (int g = 0; g < 4; g++) {
                    float pp = __builtin_amdgcn_exp2f(sc[m0][g]);
                    sc[m0][g] = pp;
                    rs += pp;
                }
            l += rs;
            // P^T -> per-wave LDS (packed b64), read back as B-frags
#pragma unroll
            for (int m0 = 0; m0 < 4; m0++) {
                bf16_t hq[4];
#pragma unroll
                for (int g = 0; g < 4; g++) hq[g] = (bf16_t)sc[m0][g];
                int elem = (m0 >> 1) * 512 + (((m0 & 1) * 2 + (quad >> 1)) * 16 + r) * 8 + (quad & 1) * 4;
                *(uint64_t*)(Pw + elem) = *(uint64_t*)hq;
            }
            __builtin_amdgcn_wave_barrier();  // Pw writes -> reads (same wave, DS in-order)
            bf16x8 pf0 = *(const bf16x8*)(Pw + lane * 8);
            bf16x8 pf1 = *(const bf16x8*)(Pw + 512 + lane * 8);
#pragma unroll
            for (int d0 = 0; d0 < 4; d0++) {
                const bf16_t* vp = Vt + (d0 * 16 + r) * 64;
                bf16x8 vf0 = *(const bf16x8*)(vp + koff0);
                bf16x8 vf1 = *(const bf16x8*)(vp + koff1);
                oacc[d0] = mfma16(vf0, pf0, oacc[d0]);
                oacc[d0] = mfma16(vf1, pf1, oacc[d0]);
            }
            // no trailing wave_barrier: next stage's Pw writes are same-wave DS ops,
            // issued after these reads -> DS pipe order guarantees WAR safety.
        }
    }
    // full row-sum: reduce l across the 4 quads (deferred from the loop)
    l += __shfl_xor(l, 16);
    l += __shfl_xor(l, 32);
    // ---- combine group partials (split-K merge) ----
    __syncthreads();  // all staging/P traffic done; LDS reusable
    float* Co = (float*)&Ks[0][0][0];  // O1: [wq][16q][64d] fp32 = 16 KB
    float* Cl = (float*)&Vs[0][0][0];  // l1[64]
    if (grp == 1) {
#pragma unroll
        for (int d0 = 0; d0 < 4; d0++)
            *(f32x4*)(Co + wq * 1024 + r * 64 + d0 * 16 + quad * 4) = oacc[d0];
        if (quad == 0) Cl[wq * 16 + r] = l;
    }
    __syncthreads();
    if (grp == 0) {
        float inv = 1.f / (l + Cl[wq * 16 + r]);
        const int b = bh >> 4, h = bh & 15;
        bf16_t* dst = att + ((size_t)(b * T_ + qrow)) * 1024 + h * 64;
#pragma unroll
        for (int d0 = 0; d0 < 4; d0++) {
            f32x4 o1 = *(const f32x4*)(Co + wq * 1024 + r * 64 + d0 * 16 + quad * 4);
            bf16_t hh[4];
#pragma unroll
            for (int g = 0; g < 4; g++)
                hh[g] = (bf16_t)((oacc[d0][g] + o1[g]) * inv);
            *(uint64_t*)(dst + d0 * 16 + quad * 4) = *(uint64_t*)hh;
        }
    }
}

// ---------------- launch ----------------
extern "C" void kernel_launch(void* const* d_in, const int* in_sizes, int n_in,
                              void* d_out, int out_size, void* d_ws, size_t ws_size,
                              hipStream_t stream) {
    const float* x = (const float*)d_in[0];
    const float* fcos = (const float*)d_in[1];
    const float* fsin = (const float*)d_in[2];
    const float* Wqkv = (const float*)d_in[3];
    const float* bqkv = (const float*)d_in[4];
    const float* Wproj = (const float*)d_in[5];
    const float* bproj = (const float*)d_in[6];
    float* out = (float*)d_out;

    uint8_t* p = (uint8_t*)d_ws;
    size_t need = 0;
    auto take = [&](size_t bytes) {
        void* q = p;
        size_t pad = (bytes + 255) & ~(size_t)255;
        p += pad;
        need += pad;
        return q;
    };
    bf16_t* xb = (bf16_t*)take((size_t)M_ * C_ * 2);         // 8 MB
    bf16_t* wqkvT = (bf16_t*)take((size_t)3 * C_ * C_ * 2);  // 6 MB
    bf16_t* wprojT = (bf16_t*)take((size_t)C_ * C_ * 2);     // 2 MB
    bf16_t* Qb = (bf16_t*)take((size_t)B_ * H_ * T_ * 64 * 2);
    bf16_t* Kb = (bf16_t*)take((size_t)B_ * H_ * T_ * 64 * 2);
    bf16_t* VTb = (bf16_t*)take((size_t)B_ * H_ * 64 * T_ * 2);
    bf16_t* attb = (bf16_t*)take((size_t)M_ * C_ * 2);
    if (ws_size < need) return;  // fail loudly (zeros) rather than corrupt

    // fused prep: cast x (2048) + transpose Wqkv (1536) + transpose Wproj (512)
    prep<<<4096, 256, 0, stream>>>(x, xb, Wqkv, wqkvT, Wproj, wprojT);

    // QKV GEMM + bias + RoPE + swizzled scatter (768 blocks, XCD-partitioned 1D, BK=64)
    gemm128<0><<<dim3(768), 256, 0, stream>>>(
        xb, wqkvT, bqkv, 3 * C_, C_, Qb, Kb, VTb, fcos, fsin, nullptr);

    // flash attention (split-K pairs of KV tiles per block, descending-t LPT dispatch)
    attn64<<<dim3(1024), 512, 0, stream>>>(Qb, Kb, VTb, attb);

    // output projection (512 blocks of 128x64, 2/CU, XCD-partitioned 1D, BK=64)
    gemm128<1><<<dim3(512), 256, 0, stream>>>(
        attb, wprojT, bproj, C_, C_, nullptr, nullptr, nullptr, nullptr, nullptr, out);
}